// Round 5
// baseline (134.537 us; speedup 1.0000x reference)
//
#include <hip/hip_runtime.h>

#define NANCH   131072
#define NMAX    64
#define NBATCH  16
#define THREADS 128
#define APT     8                       // anchors per thread
#define ACH     (THREADS * APT)         // 1024 anchors per block
#define NCHUNK  (NANCH / ACH)           // 128 anchor chunks
#define NPAIR   (NBATCH / 2)            // 8 batch pairs
#define NBLK    (NCHUNK * NPAIR)        // 1024 phase blocks
#define GTG     8                       // gt group size

// ---------------------------------------------------------------------------
// ws layout:
//   [0, 8KB)           u64 cells[NBATCH*NMAX]   packed per-gt argmax
//   [8KB, 8KB+64B)     int pairs[16]            batch pairing (balance)
//   [8256, 8256+8KB)   double partials[NBLK]
// cells packed as (iou_bits<<32)|(0x7FFFFFFF-idx): iou>=0 so float bits are
// unsigned-monotonic; ties -> larger low word -> smaller anchor index == JAX
// argmax first-occurrence semantics.
// ---------------------------------------------------------------------------

__global__ __launch_bounds__(64) void k_setup(
    const int* __restrict__ nobj, unsigned long long* __restrict__ cells,
    int* __restrict__ pairs)
{
    int tid = threadIdx.x;
    for (int i = tid; i < NBATCH * NMAX; i += 64) cells[i] = 0ull;
    if (tid == 0) {
        int idx[NBATCH], key[NBATCH];
        for (int i = 0; i < NBATCH; ++i) { idx[i] = i; key[i] = nobj[i]; }
        for (int i = 1; i < NBATCH; ++i) {            // stable insertion, desc
            int kj = key[i], ij = idx[i], j = i - 1;
            while (j >= 0 && key[j] < kj) { key[j+1]=key[j]; idx[j+1]=idx[j]; --j; }
            key[j+1] = kj; idx[j+1] = ij;
        }
        for (int p = 0; p < NPAIR; ++p) {             // big + small -> equal sums
            pairs[2*p]   = idx[p];
            pairs[2*p+1] = idx[NBATCH-1-p];
        }
    }
}

// Single pass, barrier-free main loop: each IoU computed once, feeding both
// the threshold count (focal) and the per-gt argmax. Per-WAVE atomics (no
// cross-wave LDS combine) keep the two waves fully independent.
__global__ __launch_bounds__(THREADS) void k_phase(
    const float* __restrict__ thr_p,
    const float* __restrict__ classes,   // [B,A,2]
    const float* __restrict__ anchors,   // [A,4] xyxy
    const float* __restrict__ gt,        // [B,NMAX,4] xywh
    const int*   __restrict__ nobj,
    const int*   __restrict__ pairs,
    unsigned long long* __restrict__ cells,
    double* __restrict__ partials)
{
    int chunk = blockIdx.x / NPAIR;
    int pr    = blockIdx.x % NPAIR;
    int tid   = threadIdx.x;
    float thr = *thr_p;
    int b0 = pairs[2*pr], b1 = pairs[2*pr+1];
    int no0 = nobj[b0], no1 = nobj[b1];

    __shared__ float4 sbox[2*NMAX];      // xyxy (degenerate-padded)
    __shared__ float  sgar[2*NMAX];      // gt area (0 for pads)
    {
        int j = tid;                     // 128 threads = 128 entries
        int s = j >> 6, n = j & 63;
        int b  = s ? b1 : b0;
        int no = s ? no1 : no0;
        float4 g = reinterpret_cast<const float4*>(gt)[b*NMAX + n];
        float x2 = g.x + g.z, y2 = g.y + g.w;
        float4 box = make_float4(g.x, g.y, x2, y2);
        float  ar  = (x2 - g.x) * (y2 - g.y);
        if (n >= no) { box = make_float4(4.f,4.f,4.f,4.f); ar = 0.f; } // inter=0
        sbox[j] = box; sgar[j] = ar;
    }
    __syncthreads();                     // the only barrier before epilogue

    float ax1[APT], ay1[APT], ax2[APT], ay2[APT], aar[APT];
    int   aidx[APT];
    int abase = chunk * ACH + tid;
    #pragma unroll
    for (int k = 0; k < APT; ++k) {
        aidx[k] = abase + k * THREADS;
        float4 v = reinterpret_cast<const float4*>(anchors)[aidx[k]];
        ax1[k]=v.x; ay1[k]=v.y; ax2[k]=v.z; ay2[k]=v.w;
        aar[k] = (v.z - v.x) * (v.w - v.y);
    }

    int wv = tid >> 6, ln = tid & 63;
    double acc = 0.0;

    for (int s = 0; s < 2; ++s) {
        int b    = s ? b1 : b0;
        int no   = s ? no1 : no0;
        int base = s * NMAX;
        int cnt[APT];
        #pragma unroll
        for (int k = 0; k < APT; ++k) cnt[k] = 0;

        for (int g0 = 0; g0 < no; g0 += GTG) {
            float bn[GTG], bd[GTG]; int bx[GTG];
            #pragma unroll
            for (int n = 0; n < GTG; ++n) { bn[n] = -1.f; bd[n] = 1.f; bx[n] = 0; }

            #pragma unroll
            for (int n = 0; n < GTG; ++n) {
                float4 g  = sbox[base + g0 + n];
                float gar = sgar[base + g0 + n];
                #pragma unroll
                for (int k = 0; k < APT; ++k) {
                    float lx = fmaxf(ax1[k], g.x);
                    float ly = fmaxf(ay1[k], g.y);
                    float rx = fminf(ax2[k], g.z);
                    float ry = fminf(ay2[k], g.w);
                    float w  = fmaxf(rx - lx, 0.f);
                    float h  = fmaxf(ry - ly, 0.f);
                    float inter = w * h;
                    float den   = (aar[k] + gar) - inter;   // > 0 (real gt)
                    // iou > thr  <=>  inter > thr*den      (den > 0)
                    cnt[k] += (inter > thr * den) ? 1 : 0;
                    // iouA > iouBest <=> interA*bd > bn*denA (dens > 0)
                    bool better = inter * bd[n] > bn[n] * den;
                    bn[n] = better ? inter   : bn[n];
                    bd[n] = better ? den     : bd[n];
                    bx[n] = better ? aidx[k] : bx[n];
                }
            }

            unsigned long long pk[GTG];
            #pragma unroll
            for (int n = 0; n < GTG; ++n) {
                float iou = bn[n] * __builtin_amdgcn_rcpf(bd[n]);  // order only
                pk[n] = ((unsigned long long)__float_as_uint(iou) << 32)
                      | (unsigned long long)(0x7FFFFFFFu - (unsigned)bx[n]);
            }
            #pragma unroll
            for (int off = 32; off; off >>= 1) {       // 8 interleaved chains
                #pragma unroll
                for (int n = 0; n < GTG; ++n) {
                    unsigned long long o = __shfl_xor(pk[n], off, 64);
                    if (o > pk[n]) pk[n] = o;
                }
            }
            if (ln == 0) {                             // per-WAVE atomic, no barrier
                #pragma unroll
                for (int n = 0; n < GTG; ++n)
                    if (g0 + n < no) atomicMax(&cells[b*NMAX + g0 + n], pk[n]);
            }
        }

        const float2* cp = reinterpret_cast<const float2*>(classes) + (size_t)b * NANCH;
        #pragma unroll
        for (int k = 0; k < APT; ++k) {
            float2 c = cp[aidx[k]];
            float p  = (cnt[k] > 0) ? c.y : c.x;
            float om = 1.0f - p;
            float focal = -om * om * __logf(p);
            acc += (double)(focal * (1.0f + 10.0f * (float)cnt[k]));
        }
    }

    #pragma unroll
    for (int off = 32; off; off >>= 1) acc += __shfl_xor(acc, off, 64);
    __shared__ double sw[2];
    if (ln == 0) sw[wv] = acc;
    __syncthreads();
    if (tid == 0) partials[blockIdx.x] = sw[0] + sw[1];
}

// One block, 1024 threads: sparse forced-positive correction (batch = tid>>6)
// + final reduction. Expressions textually identical to k_phase so the "old"
// contribution cancels exactly.
__global__ __launch_bounds__(1024) void k_tail(
    const float* __restrict__ thr_p,
    const float* __restrict__ classes,
    const float* __restrict__ anchors,
    const float* __restrict__ gt,
    const int*   __restrict__ nobj,
    const unsigned long long* __restrict__ cells,
    const double* __restrict__ partials,
    float* __restrict__ out)
{
    int tid = threadIdx.x;
    int b = tid >> 6, n = tid & 63;
    float thr = *thr_p;

    __shared__ float4 sbox[NBATCH*NMAX];
    __shared__ float  sar[NBATCH*NMAX];
    __shared__ int    sidx[NBATCH*NMAX];
    __shared__ double sdelta[NBATCH];
    __shared__ double sw[16];

    int n_obj = nobj[b];
    {
        float4 g = reinterpret_cast<const float4*>(gt)[b*NMAX + n];
        float x2 = g.x + g.z, y2 = g.y + g.w;
        sbox[tid] = make_float4(g.x, g.y, x2, y2);
        sar[tid]  = (x2 - g.x) * (y2 - g.y);
    }
    __syncthreads();

    int bi = -1; bool need = false;
    float4 av = make_float4(0.f,0.f,0.f,0.f);
    float aar = 0.f;
    if (n < n_obj) {
        unsigned long long pkv = cells[tid];
        bi = (int)(0x7FFFFFFFu - (unsigned)(pkv & 0xFFFFFFFFull));
        av = reinterpret_cast<const float4*>(anchors)[bi];
        aar = (av.z - av.x) * (av.w - av.y);
        float4 g = sbox[tid];
        float lx = fmaxf(av.x, g.x), ly = fmaxf(av.y, g.y);
        float rx = fminf(av.z, g.z), ry = fminf(av.w, g.w);
        float w  = fmaxf(rx - lx, 0.f), h = fmaxf(ry - ly, 0.f);
        float inter = w * h;
        float den   = (aar + sar[tid]) - inter;
        need = !(inter > thr * den);     // forced adds a bit only if !pos
    }
    sidx[tid] = need ? bi : -1;
    __syncthreads();

    double delta = 0.0;
    if (need) {
        bool first = true; int extra = 0;
        int base = b * NMAX;
        for (int m = 0; m < NMAX; ++m) {
            if (sidx[base + m] == bi) { if (m < n) first = false; ++extra; }
        }
        if (first) {
            int count = 0;
            for (int m = 0; m < n_obj; ++m) {
                float4 g = sbox[base + m];
                float lx = fmaxf(av.x, g.x), ly = fmaxf(av.y, g.y);
                float rx = fminf(av.z, g.z), ry = fminf(av.w, g.w);
                float w  = fmaxf(rx - lx, 0.f), h = fmaxf(ry - ly, 0.f);
                float inter = w * h;
                float den   = (aar + sar[base + m]) - inter;
                count += (inter > thr * den) ? 1 : 0;
            }
            float2 c = reinterpret_cast<const float2*>(classes)[(size_t)b * NANCH + bi];
            float po = (count > 0) ? c.y : c.x;
            float oo = 1.f - po;
            float fo = -oo * oo * __logf(po);
            float oldc = fo * (1.f + 10.f * (float)count);
            int cn = count + extra;
            float pn = (cn > 0) ? c.y : c.x;
            float on = 1.f - pn;
            float fn = -on * on * __logf(pn);
            float newc = fn * (1.f + 10.f * (float)cn);
            delta = (double)newc - (double)oldc;
        }
    }
    #pragma unroll
    for (int off = 32; off; off >>= 1) delta += __shfl_xor(delta, off, 64);
    if (n == 0) sdelta[b] = delta;
    __syncthreads();

    // final: NBLK(=1024) partials map 1:1 to threads, plus 16 deltas
    double v = partials[tid];
    if (tid < NBATCH) v += sdelta[tid];
    #pragma unroll
    for (int off = 32; off; off >>= 1) v += __shfl_xor(v, off, 64);
    if ((tid & 63) == 0) sw[tid >> 6] = v;
    __syncthreads();
    if (tid == 0) {
        double tot = 0.0;
        #pragma unroll
        for (int i = 0; i < 16; ++i) tot += sw[i];
        double cls = tot * (0.01 / 16.0);
        out[0] = (float)cls;   // total = class + coord(0)
        out[1] = (float)cls;
        out[2] = 0.0f;
    }
}

extern "C" void kernel_launch(void* const* d_in, const int* in_sizes, int n_in,
                              void* d_out, int out_size, void* d_ws, size_t ws_size,
                              hipStream_t stream) {
    const float* thr     = (const float*)d_in[0];
    const float* classes = (const float*)d_in[1];
    const float* anchors = (const float*)d_in[2];
    const float* gt      = (const float*)d_in[3];
    const int*   nobj    = (const int*)d_in[4];
    float* out = (float*)d_out;

    unsigned long long* cells = (unsigned long long*)d_ws;
    int*    pairs    = (int*)((char*)d_ws + NBATCH * NMAX * sizeof(unsigned long long));
    double* partials = (double*)((char*)d_ws + NBATCH * NMAX * sizeof(unsigned long long) + 64);

    k_setup<<<1, 64, 0, stream>>>(nobj, cells, pairs);
    k_phase<<<NBLK, THREADS, 0, stream>>>(thr, classes, anchors, gt, nobj, pairs,
                                          cells, partials);
    k_tail<<<1, 1024, 0, stream>>>(thr, classes, anchors, gt, nobj, cells, partials, out);
}

// Round 6
// 89.296 us; speedup vs baseline: 1.5066x; 1.5066x over previous
//
#include <hip/hip_runtime.h>

#define NANCH   131072
#define NMAX    64
#define NBATCH  16
#define THREADS 256
#define APT     4                       // anchors per thread
#define ACH     (THREADS * APT)         // 1024 anchors per block
#define NCHUNK  (NANCH / ACH)           // 128 anchor chunks
#define NPAIR   (NBATCH / 2)            // 8 batch pairs
#define NBLK    (NCHUNK * NPAIR)        // 1024 phase blocks
#define GTG     8                       // gt group size
#define NGRPMX  (NMAX / GTG)            // 8 groups per batch

// ---------------------------------------------------------------------------
// ws layout:
//   [0, 8KB)           u64 cells[NBATCH*NMAX]   packed per-gt argmax
//   [8KB, 8KB+64B)     int pairs[16]            batch pairing (balance)
//   [8256, 8256+8KB)   double partials[NBLK]
// cells packed as (iou_bits<<32)|(0x7FFFFFFF-idx): iou>=0 so float bits are
// unsigned-monotonic; ties -> larger low word -> smaller anchor index == JAX
// argmax first-occurrence semantics.
// ---------------------------------------------------------------------------

__global__ __launch_bounds__(64) void k_setup(
    const int* __restrict__ nobj, unsigned long long* __restrict__ cells,
    int* __restrict__ pairs)
{
    int tid = threadIdx.x;
    for (int i = tid; i < NBATCH * NMAX; i += 64) cells[i] = 0ull;
    if (tid == 0) {
        int idx[NBATCH], key[NBATCH];
        for (int i = 0; i < NBATCH; ++i) { idx[i] = i; key[i] = nobj[i]; }
        for (int i = 1; i < NBATCH; ++i) {            // stable insertion, desc
            int kj = key[i], ij = idx[i], j = i - 1;
            while (j >= 0 && key[j] < kj) { key[j+1]=key[j]; idx[j+1]=idx[j]; --j; }
            key[j+1] = kj; idx[j+1] = ij;
        }
        for (int p = 0; p < NPAIR; ++p) {             // big + small -> equal sums
            pairs[2*p]   = idx[p];
            pairs[2*p+1] = idx[NBATCH-1-p];
        }
    }
}

// Single pass: each IoU computed once, feeding both the threshold count
// (focal) and the per-gt argmax. Main loop is barrier-free: per-group wave
// results go to per-wave LDS slots; atomics fire ONCE per batch (one
// wave-wide instruction), so no per-group vmcnt drain stalls.
__global__ __launch_bounds__(THREADS) void k_phase(
    const float* __restrict__ thr_p,
    const float* __restrict__ classes,   // [B,A,2]
    const float* __restrict__ anchors,   // [A,4] xyxy
    const float* __restrict__ gt,        // [B,NMAX,4] xywh
    const int*   __restrict__ nobj,
    const int*   __restrict__ pairs,
    unsigned long long* __restrict__ cells,
    double* __restrict__ partials)
{
    int chunk = blockIdx.x / NPAIR;
    int pr    = blockIdx.x % NPAIR;
    int tid   = threadIdx.x;
    float thr = *thr_p;
    int b0 = pairs[2*pr], b1 = pairs[2*pr+1];
    int no0 = nobj[b0], no1 = nobj[b1];

    __shared__ float4 sbox[2*NMAX];                    // xyxy (degenerate-padded)
    __shared__ float  sgar[2*NMAX];                    // gt area (0 for pads)
    __shared__ unsigned long long spk[4][NGRPMX][GTG]; // per-wave group results
    __shared__ double sw[4];

    for (int j = tid; j < 2*NMAX; j += THREADS) {
        int s = j >> 6, n = j & 63;
        int b  = s ? b1 : b0;
        int no = s ? no1 : no0;
        float4 g = reinterpret_cast<const float4*>(gt)[b*NMAX + n];
        float x2 = g.x + g.z, y2 = g.y + g.w;
        float4 box = make_float4(g.x, g.y, x2, y2);
        float  ar  = (x2 - g.x) * (y2 - g.y);
        if (n >= no) { box = make_float4(4.f,4.f,4.f,4.f); ar = 0.f; } // inter=0
        sbox[j] = box; sgar[j] = ar;
    }
    __syncthreads();

    float ax1[APT], ay1[APT], ax2[APT], ay2[APT], aar[APT];
    int   aidx[APT];
    int abase = chunk * ACH + tid;
    #pragma unroll
    for (int k = 0; k < APT; ++k) {
        aidx[k] = abase + k * THREADS;
        float4 v = reinterpret_cast<const float4*>(anchors)[aidx[k]];
        ax1[k]=v.x; ay1[k]=v.y; ax2[k]=v.z; ay2[k]=v.w;
        aar[k] = (v.z - v.x) * (v.w - v.y);
    }

    int wv = tid >> 6, ln = tid & 63;
    double acc = 0.0;

    for (int s = 0; s < 2; ++s) {
        int b    = s ? b1 : b0;
        int no   = s ? no1 : no0;
        int base = s * NMAX;
        int cnt[APT];
        #pragma unroll
        for (int k = 0; k < APT; ++k) cnt[k] = 0;

        for (int g0 = 0; g0 < no; g0 += GTG) {
            float bn[GTG], bd[GTG]; int bx[GTG];
            #pragma unroll
            for (int n = 0; n < GTG; ++n) { bn[n] = -1.f; bd[n] = 1.f; bx[n] = 0; }

            #pragma unroll
            for (int n = 0; n < GTG; ++n) {
                float4 g  = sbox[base + g0 + n];
                float gar = sgar[base + g0 + n];
                #pragma unroll
                for (int k = 0; k < APT; ++k) {
                    float lx = fmaxf(ax1[k], g.x);
                    float ly = fmaxf(ay1[k], g.y);
                    float rx = fminf(ax2[k], g.z);
                    float ry = fminf(ay2[k], g.w);
                    float w  = fmaxf(rx - lx, 0.f);
                    float h  = fmaxf(ry - ly, 0.f);
                    float inter = w * h;
                    float den   = (aar[k] + gar) - inter;   // > 0 (real gt)
                    // iou > thr  <=>  inter > thr*den      (den > 0)
                    cnt[k] += (inter > thr * den) ? 1 : 0;
                    // iouA > iouBest <=> interA*bd > bn*denA (dens > 0)
                    bool better = inter * bd[n] > bn[n] * den;
                    bn[n] = better ? inter   : bn[n];
                    bd[n] = better ? den     : bd[n];
                    bx[n] = better ? aidx[k] : bx[n];
                }
            }

            unsigned long long pk[GTG];
            #pragma unroll
            for (int n = 0; n < GTG; ++n) {
                float iou = bn[n] * __builtin_amdgcn_rcpf(bd[n]);  // order only
                pk[n] = ((unsigned long long)__float_as_uint(iou) << 32)
                      | (unsigned long long)(0x7FFFFFFFu - (unsigned)bx[n]);
            }
            #pragma unroll
            for (int off = 32; off; off >>= 1) {       // 8 interleaved chains
                #pragma unroll
                for (int n = 0; n < GTG; ++n) {
                    unsigned long long o = __shfl_xor(pk[n], off, 64);
                    if (o > pk[n]) pk[n] = o;
                }
            }
            if (ln == 0) {                             // per-wave slot, no barrier
                int grp = g0 >> 3;
                #pragma unroll
                for (int n = 0; n < GTG; ++n) spk[wv][grp][n] = pk[n];
            }
        }

        __syncthreads();                               // all waves' spk visible
        if (tid < no) {                                // one atomic instr / batch
            int grp = tid >> 3, slot = tid & 7;
            unsigned long long m0 = spk[0][grp][slot] > spk[1][grp][slot]
                                  ? spk[0][grp][slot] : spk[1][grp][slot];
            unsigned long long m1 = spk[2][grp][slot] > spk[3][grp][slot]
                                  ? spk[2][grp][slot] : spk[3][grp][slot];
            unsigned long long m  = m0 > m1 ? m0 : m1;
            atomicMax(&cells[b*NMAX + tid], m);
        }
        __syncthreads();                               // protect spk reuse

        const float2* cp = reinterpret_cast<const float2*>(classes) + (size_t)b * NANCH;
        #pragma unroll
        for (int k = 0; k < APT; ++k) {
            float2 c = cp[aidx[k]];
            float p  = (cnt[k] > 0) ? c.y : c.x;
            float om = 1.0f - p;
            float focal = -om * om * __logf(p);
            acc += (double)(focal * (1.0f + 10.0f * (float)cnt[k]));
        }
    }

    #pragma unroll
    for (int off = 32; off; off >>= 1) acc += __shfl_xor(acc, off, 64);
    if (ln == 0) sw[wv] = acc;
    __syncthreads();
    if (tid == 0) partials[blockIdx.x] = sw[0] + sw[1] + sw[2] + sw[3];
}

// One block, 1024 threads: sparse forced-positive correction (batch = tid>>6)
// + final reduction. Expressions textually identical to k_phase so the "old"
// contribution cancels exactly.
__global__ __launch_bounds__(1024) void k_tail(
    const float* __restrict__ thr_p,
    const float* __restrict__ classes,
    const float* __restrict__ anchors,
    const float* __restrict__ gt,
    const int*   __restrict__ nobj,
    const unsigned long long* __restrict__ cells,
    const double* __restrict__ partials,
    float* __restrict__ out)
{
    int tid = threadIdx.x;
    int b = tid >> 6, n = tid & 63;
    float thr = *thr_p;

    __shared__ float4 sbox[NBATCH*NMAX];
    __shared__ float  sar[NBATCH*NMAX];
    __shared__ int    sidx[NBATCH*NMAX];
    __shared__ double sdelta[NBATCH];
    __shared__ double sw[16];

    int n_obj = nobj[b];
    {
        float4 g = reinterpret_cast<const float4*>(gt)[b*NMAX + n];
        float x2 = g.x + g.z, y2 = g.y + g.w;
        sbox[tid] = make_float4(g.x, g.y, x2, y2);
        sar[tid]  = (x2 - g.x) * (y2 - g.y);
    }
    __syncthreads();

    int bi = -1; bool need = false;
    float4 av = make_float4(0.f,0.f,0.f,0.f);
    float aar = 0.f;
    if (n < n_obj) {
        unsigned long long pkv = cells[tid];
        bi = (int)(0x7FFFFFFFu - (unsigned)(pkv & 0xFFFFFFFFull));
        av = reinterpret_cast<const float4*>(anchors)[bi];
        aar = (av.z - av.x) * (av.w - av.y);
        float4 g = sbox[tid];
        float lx = fmaxf(av.x, g.x), ly = fmaxf(av.y, g.y);
        float rx = fminf(av.z, g.z), ry = fminf(av.w, g.w);
        float w  = fmaxf(rx - lx, 0.f), h = fmaxf(ry - ly, 0.f);
        float inter = w * h;
        float den   = (aar + sar[tid]) - inter;
        need = !(inter > thr * den);     // forced adds a bit only if !pos
    }
    sidx[tid] = need ? bi : -1;
    __syncthreads();

    double delta = 0.0;
    if (need) {
        bool first = true; int extra = 0;
        int base = b * NMAX;
        for (int m = 0; m < NMAX; ++m) {
            if (sidx[base + m] == bi) { if (m < n) first = false; ++extra; }
        }
        if (first) {
            int count = 0;
            for (int m = 0; m < n_obj; ++m) {
                float4 g = sbox[base + m];
                float lx = fmaxf(av.x, g.x), ly = fmaxf(av.y, g.y);
                float rx = fminf(av.z, g.z), ry = fminf(av.w, g.w);
                float w  = fmaxf(rx - lx, 0.f), h = fmaxf(ry - ly, 0.f);
                float inter = w * h;
                float den   = (aar + sar[base + m]) - inter;
                count += (inter > thr * den) ? 1 : 0;
            }
            float2 c = reinterpret_cast<const float2*>(classes)[(size_t)b * NANCH + bi];
            float po = (count > 0) ? c.y : c.x;
            float oo = 1.f - po;
            float fo = -oo * oo * __logf(po);
            float oldc = fo * (1.f + 10.f * (float)count);
            int cn = count + extra;
            float pn = (cn > 0) ? c.y : c.x;
            float on = 1.f - pn;
            float fn = -on * on * __logf(pn);
            float newc = fn * (1.f + 10.f * (float)cn);
            delta = (double)newc - (double)oldc;
        }
    }
    #pragma unroll
    for (int off = 32; off; off >>= 1) delta += __shfl_xor(delta, off, 64);
    if (n == 0) sdelta[b] = delta;
    __syncthreads();

    // final: NBLK(=1024) partials map 1:1 to threads, plus 16 deltas
    double v = partials[tid];
    if (tid < NBATCH) v += sdelta[tid];
    #pragma unroll
    for (int off = 32; off; off >>= 1) v += __shfl_xor(v, off, 64);
    if ((tid & 63) == 0) sw[tid >> 6] = v;
    __syncthreads();
    if (tid == 0) {
        double tot = 0.0;
        #pragma unroll
        for (int i = 0; i < 16; ++i) tot += sw[i];
        double cls = tot * (0.01 / 16.0);
        out[0] = (float)cls;   // total = class + coord(0)
        out[1] = (float)cls;
        out[2] = 0.0f;
    }
}

extern "C" void kernel_launch(void* const* d_in, const int* in_sizes, int n_in,
                              void* d_out, int out_size, void* d_ws, size_t ws_size,
                              hipStream_t stream) {
    const float* thr     = (const float*)d_in[0];
    const float* classes = (const float*)d_in[1];
    const float* anchors = (const float*)d_in[2];
    const float* gt      = (const float*)d_in[3];
    const int*   nobj    = (const int*)d_in[4];
    float* out = (float*)d_out;

    unsigned long long* cells = (unsigned long long*)d_ws;
    int*    pairs    = (int*)((char*)d_ws + NBATCH * NMAX * sizeof(unsigned long long));
    double* partials = (double*)((char*)d_ws + NBATCH * NMAX * sizeof(unsigned long long) + 64);

    k_setup<<<1, 64, 0, stream>>>(nobj, cells, pairs);
    k_phase<<<NBLK, THREADS, 0, stream>>>(thr, classes, anchors, gt, nobj, pairs,
                                          cells, partials);
    k_tail<<<1, 1024, 0, stream>>>(thr, classes, anchors, gt, nobj, cells, partials, out);
}